// Round 9
// baseline (105.920 us; speedup 1.0000x reference)
//
#include <hip/hip_runtime.h>
#include <cstddef>

namespace {
constexpr int cB = 64, cN = 34, cF = 16, cT = 96, cK = 3, cO = 64;
constexpr int LP = 72;    // u16 pitch (144B rows: 16B-aligned frags, 2-way-free banks)
constexpr int GP = 64;    // gsT u16 pitch (k-dim padded to 64)
constexpr int BHP = 88;   // kernel-B H pitch (176B rows: 16B-aligned, 2-way-free)
constexpr int T4 = cT / 4;
constexpr float cEPS = 1e-8f;

typedef __attribute__((ext_vector_type(8))) _Float16 f16x8;
typedef __attribute__((ext_vector_type(4))) float   f32x4;

__device__ inline unsigned short f2h(float v) {
    _Float16 h = (_Float16)v;
    return __builtin_bit_cast(unsigned short, h);
}
__device__ inline float h2f(unsigned short u) {
    return (float)__builtin_bit_cast(_Float16, u);
}

// H staging address inside d_out (dword index). s = tt*40 + c_dw, s < 160.
// Slots for tile (b,t4) live only in out[:, o<40, 4*t4 .. 4*t4+3] -> each proj_k
// block reads exactly the slots its own final stores later overwrite: race-free.
__device__ inline size_t hstage_idx(int b, int t4, int j, int s) {
    return (((size_t)b * cN + j) * cO + (s >> 2)) * cT + 4 * t4 + (s & 3);
}
}

// ---------------- softmax over axis=2 (i) of st_attention (B,K,N,N) ----------------
__global__ __launch_bounds__(256) void att_softmax_k(const float* __restrict__ st,
                                                     float* __restrict__ att) {
    int idx = blockIdx.x * blockDim.x + threadIdx.x;
    if (idx >= cB * cK * cN) return;
    int j = idx % cN;
    int bk = idx / cN;
    const float* base = st + (size_t)bk * cN * cN + j;
    float v[cN];
    float m = -3.402823466e38f;
#pragma unroll
    for (int i = 0; i < cN; ++i) { v[i] = base[(size_t)i * cN]; m = fmaxf(m, v[i]); }
    float s = 0.f;
#pragma unroll
    for (int i = 0; i < cN; ++i) { v[i] = __expf(v[i] - m); s += v[i]; }
    float inv = 1.f / s;
    float* ob = att + (size_t)bk * cN * cN + j;
#pragma unroll
    for (int i = 0; i < cN; ++i) ob[(size_t)i * cN] = v[i] * inv;
}

// ---------------- kernel A: one block per (b,t); H(34x80 fp16) -> staged in out ----------------
__global__ __launch_bounds__(256, 5) void cheb_h_k(
    const float* __restrict__ x,      // (B,N,F,T)
    const float* __restrict__ att,    // (B,K,N,N) softmaxed
    const float* __restrict__ pos,    // (N,2)
    const float* __restrict__ dist,   // (N,N)
    unsigned* __restrict__ Hst)       // = (unsigned*)out, staging slots
{
    // fp16 matrices [34][LP]; cols >=34 zero (k-pad). A-frag row-overrun reads
    // (rows 34..47, up to 2000B past an array) must land in allocated LDS ->
    // declaration order matters; M3T overruns into gsT+floats (3000B) OK.
    __shared__ __align__(16) unsigned short s_L1[cN * LP];   // A fp32 overlay; L1; then M2T
    __shared__ __align__(16) unsigned short s_L2[cN * LP];   // L2; then M4T
    __shared__ __align__(16) unsigned short s_LT1[cN * LP];  // L1^T (vector B-op of C1)
    __shared__ __align__(16) unsigned short s_LT2[cN * LP];  // L2^T (vector B-op of C2)
    __shared__ __align__(16) unsigned short s_M1T[cN * LP];  // att1 .* L1, transposed
    __shared__ __align__(16) unsigned short s_M3T[cN * LP];  // att1 .* L2, transposed
    __shared__ __align__(16) unsigned short s_gsT[cF * GP];  // gs^T fp16 (single-writer fill)
    __shared__ float s_d0[cN], s_v1[cN], s_v2[cN], s_p1[cN], s_p2[cN], s_di1[cN], s_di2[cN];

    const int tid = threadIdx.x;
    const int lane = tid & 63;
    const int w = tid >> 6;
    const int lr = lane & 15;
    const int lg = lane >> 4;
    const int kb8 = lg * 8;

    // XCD swizzle (grid 6144, %8==0 -> bijective)
    const unsigned g = blockIdx.x;
    const unsigned lin = (g & 7u) * (cB * cT / 8) + (g >> 3);
    const int b = lin / cT, t = lin % cT;
    const int t4 = t >> 2, tt = t & 3;

    // ---- init: zero matrix pads, stage p-hat/d0/v'/gsT ----
    for (int i2 = tid; i2 < cN * LP / 2; i2 += 256) {
        ((unsigned*)s_L1)[i2] = 0u; ((unsigned*)s_L2)[i2] = 0u;
        ((unsigned*)s_LT1)[i2] = 0u; ((unsigned*)s_LT2)[i2] = 0u;
        ((unsigned*)s_M1T)[i2] = 0u; ((unsigned*)s_M3T)[i2] = 0u;
    }
    if (tid < cN) {
        float px = pos[2 * tid], py = pos[2 * tid + 1];
        float pn = sqrtf(px * px + py * py);
        float r = 1.f / fmaxf(pn, cEPS);
        s_p1[tid] = px * r; s_p2[tid] = py * r;
        s_d0[tid] = att[((size_t)b * cK) * cN * cN + tid * cN + tid];
    } else if (tid >= 64 && tid < 64 + cN) {
        int n = tid - 64;
        float x1 = x[(((size_t)b * cN + n) * cF + 1) * cT + t];
        float x2 = x[(((size_t)b * cN + n) * cF + 2) * cT + t];
        float vn = sqrtf(x1 * x1 + x2 * x2);
        float s = vn / fmaxf(vn, cEPS);
        s_v1[n] = x1 * s; s_v2[n] = x2 * s;
    }
    // single-writer gsT fill: data for n<34, zero pads for n>=34 (race lesson, r8)
    for (int idx = tid; idx < cF * GP; idx += 256) {
        int f = idx >> 6, n = idx & 63;
        unsigned short v = 0;
        if (n < cN) v = f2h(x[(((size_t)b * cN + n) * cF + f) * cT + t]);
        s_gsT[idx] = v;
    }
    __syncthreads();  // b1

    // ---- P2: adjacency A fp32, pitch 36 floats (16B-aligned rows), over s_L1 ----
    float* Af = (float*)s_L1;
#pragma unroll
    for (int e = 0; e < 5; ++e) {
        int idx = tid + 256 * e;
        if (idx < cN * cN) {
            int i = idx / cN, m = idx - i * cN;
            float dot = s_v1[i] * s_p1[m] + s_v2[i] * s_p2[m];
            Af[i * 36 + m] = __fdividef(fmaxf(dot, 0.f), dist[idx]);
        }
    }
    __syncthreads();  // b2

    // ---- P2b: degrees, 2 threads per sum (17 elems each + shfl combine) ----
    if (tid < 136) {
        int s = tid >> 1, half = tid & 1;
        float acc = 0.f;
        if (s < cN) {
            const float* row = Af + s * 36 + half * 17;
#pragma unroll
            for (int m = 0; m < 17; ++m) acc += row[m];
        } else {
            int j = s - cN;
            const float* col = Af + half * 17 * 36 + j;
#pragma unroll
            for (int i = 0; i < 17; ++i) acc += col[i * 36];
        }
        float tot = acc + __shfl_xor(acc, 1, 64);
        if (half == 0) {
            float d = (tot > 0.f) ? rsqrtf(fmaxf(tot, 1e-12f)) : 0.f;
            if (s < cN) s_di1[s] = d; else s_di2[s - cN] = d;
        }
    }
    // stash A pairs in regs before P3 overwrites the region
    float aij[5], aji[5];
#pragma unroll
    for (int e = 0; e < 5; ++e) {
        int idx = tid + 256 * e;
        if (idx < cN * cN) {
            int i = idx / cN, j = idx - i * cN;
            aij[e] = Af[i * 36 + j];
            aji[e] = Af[j * 36 + i];
        }
    }
    __syncthreads();  // b3

    // ---- P3: L1/L2 + transposes (re-zero pads dirtied by fp32-A) ----
    const float* att1 = att + ((size_t)b * cK + 1) * cN * cN;
    const float* att2 = att + ((size_t)b * cK + 2) * cN * cN;
#pragma unroll
    for (int e = 0; e < 5; ++e) {
        int idx = tid + 256 * e;
        if (idx < cN * cN) {
            int i = idx / cN, j = idx - i * cN;
            float diag = (i == j) ? 1.f : 0.f;
            float l1 = diag - s_di1[i] * aij[e] * s_di1[j];
            float l2 = diag - s_di2[i] * aji[e] * s_di2[j];
            unsigned short h1 = f2h(l1), h2b = f2h(l2);
            int rm = i * LP + j, tm = j * LP + i;
            s_L1[rm] = h1;
            s_L1[rm + cN] = 0;                       // pad cols 34..67
            if (j < 4) s_L1[i * LP + 68 + j] = 0;    // pad cols 68..71
            s_L2[rm] = h2b;
            s_LT1[tm] = h1;
            s_LT2[tm] = h2b;
            float a1 = att1[idx];
            s_M1T[tm] = f2h(a1 * l1);
            s_M3T[tm] = f2h(a1 * l2);
        }
    }
    __syncthreads();  // b4

    // ---- P4: C = L@L fp16 MFMA, all-vector operands (B from LT rows) ----
    const unsigned short* Ah = (w < 2) ? s_L1 : s_L2;
    const unsigned short* At = (w < 2) ? s_LT1 : s_LT2;
    const int nnt = (w & 1) ? 1 : 2;
    const int ntb0 = (w & 1) ? 32 : 0;
    f32x4 cd0[3], cd1[3];
#pragma unroll
    for (int mt = 0; mt < 3; ++mt) {
        cd0[mt] = (f32x4){0.f, 0.f, 0.f, 0.f};
        cd1[mt] = (f32x4){0.f, 0.f, 0.f, 0.f};
    }
#pragma unroll
    for (int ks = 0; ks < 2; ++ks) {
        f16x8 fah[3];
#pragma unroll
        for (int mt = 0; mt < 3; ++mt)
            fah[mt] = *(const f16x8*)&Ah[(mt * 16 + lr) * LP + 32 * ks + kb8];
#pragma unroll
        for (int un = 0; un < 2; ++un) {
            if (un == 1 && nnt < 2) break;
            int col = ntb0 + un * 16 + lr;
            f16x8 fb = *(const f16x8*)&At[col * LP + 32 * ks + kb8];
#pragma unroll
            for (int mt = 0; mt < 3; ++mt) {
                f32x4 acc = un ? cd1[mt] : cd0[mt];
                acc = __builtin_amdgcn_mfma_f32_16x16x32_f16(fah[mt], fb, acc, 0, 0, 0);
                if (un) cd1[mt] = acc; else cd0[mt] = acc;
            }
        }
    }
    __syncthreads();  // b5: all L/LT reads done before M2T/M4T overlay writes

    // ---- P5: M2T = att2 .* (2C1 - I) into s_L1; M4T into s_L2 ----
    {
        unsigned short* Md = (w < 2) ? s_L1 : s_L2;
#pragma unroll
        for (int un = 0; un < 2; ++un) {
            if (un == 1 && nnt < 2) break;
            int jb = ntb0 + un * 16 + lr;
            if (jb < cN) {
#pragma unroll
                for (int mt = 0; mt < 3; ++mt) {
#pragma unroll
                    for (int r = 0; r < 4; ++r) {
                        int i = mt * 16 + lg * 4 + r;
                        if (i < cN) {
                            float dv = un ? cd1[mt][r] : cd0[mt][r];
                            float cv = 2.f * dv - ((i == jb) ? 1.f : 0.f);
                            Md[jb * LP + i] = f2h(att2[i * cN + jb] * cv);
                        }
                    }
                }
            }
        }
    }
    __syncthreads();  // b6

    // ---- P6: H_p = M_p^T @ gs (wave w -> p=w+1); direct global stores ----
    {
        const unsigned short* Ap = (w == 0) ? s_M1T : (w == 1) ? s_L1
                                 : (w == 2) ? s_M3T : s_L2;
        f32x4 hd[3];
#pragma unroll
        for (int mt = 0; mt < 3; ++mt) hd[mt] = (f32x4){0.f, 0.f, 0.f, 0.f};
#pragma unroll
        for (int ks = 0; ks < 2; ++ks) {
            f16x8 fb = *(const f16x8*)&s_gsT[lr * GP + 32 * ks + kb8];
#pragma unroll
            for (int mt = 0; mt < 3; ++mt) {
                f16x8 fa = *(const f16x8*)&Ap[(mt * 16 + lr) * LP + 32 * ks + kb8];
                hd[mt] = __builtin_amdgcn_mfma_f32_16x16x32_f16(fa, fb, hd[mt], 0, 0, 0);
            }
        }
        // p0 diag block (cols 0..15 = dwords 0..7), all threads
        for (int idx = tid; idx < cN * 8; idx += 256) {
            int j = idx >> 3, c = idx & 7;
            float d = s_d0[j];
            unsigned short lo = f2h(d * h2f(s_gsT[(2 * c) * GP + j]));
            unsigned short hi = f2h(d * h2f(s_gsT[(2 * c + 1) * GP + j]));
            Hst[hstage_idx(b, t4, j, tt * 40 + c)] = (unsigned)lo | ((unsigned)hi << 16);
        }
        // pack lane pairs (cols pc+lr, pc+lr^1) -> one dword; split stores by r
        const int pc = 16 * (w + 1);
        const int cdw = (pc >> 1) + (lr >> 1);
#pragma unroll
        for (int mt = 0; mt < 3; ++mt) {
#pragma unroll
            for (int r = 0; r < 4; ++r) {
                int j = mt * 16 + lg * 4 + r;
                unsigned mine = (unsigned)f2h(hd[mt][r]);
                unsigned other = __shfl_xor(mine, 1, 64);
                unsigned dword = (lr & 1) ? ((other & 0xffffu) | (mine << 16))
                                          : (mine | (other << 16));
                bool mystore = ((lr & 1) == 0) ? (r < 2) : (r >= 2);
                if (mystore && j < cN)
                    Hst[hstage_idx(b, t4, j, tt * 40 + cdw)] = dword;
            }
        }
    }
}

// ---------------- kernel B: one block per (b,t4); out = relu(H @ Thcat) ----------------
// Reads its own staging slots into LDS (barrier), then overwrites exactly those
// t-columns with final output -> no cross-block hazard by construction.
__global__ __launch_bounds__(256, 4) void proj_k(
    const unsigned* __restrict__ Hst,   // staging view of out
    const float* __restrict__ Th,       // (K,F,O)
    const float* __restrict__ ThL,      // (K,F,O)
    float* __restrict__ out)            // (B,N,O,T)
{
    __shared__ __align__(16) unsigned short s_H[144 * BHP + 16];  // +16: A-frag overrun pad

    const int tid = threadIdx.x;
    const int lane = tid & 63;
    const int w = tid >> 6;
    const int lr = lane & 15;
    const int lg = lane >> 4;
    const int kb8 = lg * 8;
    const int ocol = w * 16 + lr;

    const unsigned g = blockIdx.x;
    const unsigned lin = (g & 7u) * (cB * T4 / 8) + (g >> 3);
    const int b = lin / T4, t4 = lin % T4;
    const int t0 = t4 * 4;

    // ---- Theta B-fragments fp16 (c = p*16+f; p0 = Th0+ThL0 merged) ----
    f16x8 bfr[3];
#pragma unroll
    for (int s = 0; s < 3; ++s) {
#pragma unroll
        for (int j = 0; j < 8; ++j) {
            int cc = 32 * s + kb8 + j;
            float v = 0.f;
            if (cc < 80) {
                int p = cc >> 4, f = cc & 15;
                if (p == 0)      v = Th[f * cO + ocol] + ThL[f * cO + ocol];
                else if (p == 1) v = Th[(cF + f) * cO + ocol];
                else if (p == 2) v = Th[(2 * cF + f) * cO + ocol];
                else if (p == 3) v = ThL[(cF + f) * cO + ocol];
                else             v = ThL[(2 * cF + f) * cO + ocol];
            }
            bfr[s][j] = (_Float16)v;
        }
    }

    // ---- load H tile from staging slots into pitch-BHP LDS; pads zero ----
    {
        unsigned* dst = (unsigned*)s_H;
        for (int i2 = tid; i2 < 144 * (BHP / 2); i2 += 256) {
            int r = i2 / (BHP / 2), c = i2 - r * (BHP / 2);
            unsigned v = 0u;
            if (r < 136 && c < 40) {
                int j = r >> 2, tt = r & 3;
                v = Hst[hstage_idx(b, t4, j, tt * 40 + c)];
            }
            dst[i2] = v;
        }
    }
    __syncthreads();

    // ---- MFMA: 9 m-tiles x 3 k-steps per wave ----
    f32x4 acc[9];
#pragma unroll
    for (int mt = 0; mt < 9; ++mt) acc[mt] = (f32x4){0.f, 0.f, 0.f, 0.f};
#pragma unroll
    for (int s = 0; s < 3; ++s) {
#pragma unroll
        for (int mt = 0; mt < 9; ++mt) {
            f16x8 a = *(const f16x8*)&s_H[(mt * 16 + lr) * BHP + kb8 + 32 * s];
            acc[mt] = __builtin_amdgcn_mfma_f32_16x16x32_f16(a, bfr[s], acc[mt], 0, 0, 0);
        }
    }

    // ---- stores: acc[mt] = out[j=4mt+lg, ocol, t0..t0+3] -> one float4 ----
#pragma unroll
    for (int mt = 0; mt < 9; ++mt) {
        int j = 4 * mt + lg;
        if (j < cN) {
            float4 v;
            v.x = fmaxf(acc[mt][0], 0.f);
            v.y = fmaxf(acc[mt][1], 0.f);
            v.z = fmaxf(acc[mt][2], 0.f);
            v.w = fmaxf(acc[mt][3], 0.f);
            *(float4*)&out[(((size_t)b * cN + j) * cO + ocol) * cT + t0] = v;
        }
    }
}

extern "C" void kernel_launch(void* const* d_in, const int* in_sizes, int n_in,
                              void* d_out, int out_size, void* d_ws, size_t ws_size,
                              hipStream_t stream) {
    const float* x    = (const float*)d_in[0];
    const float* st   = (const float*)d_in[1];
    const float* pos  = (const float*)d_in[2];
    const float* dist = (const float*)d_in[3];
    const float* Th   = (const float*)d_in[4];
    const float* ThL  = (const float*)d_in[5];
    float* out = (float*)d_out;
    float* att = (float*)d_ws;                 // 888 KB fp32 (proven ws usage)
    unsigned* Hst = (unsigned*)d_out;          // H staged inside out, race-free layout

    att_softmax_k<<<(cB * cK * cN + 255) / 256, 256, 0, stream>>>(st, att);
    cheb_h_k<<<cB * cT, 256, 0, stream>>>(x, att, pos, dist, Hst);
    proj_k<<<cB * T4, 256, 0, stream>>>(Hst, Th, ThL, out);
}

// Round 10
// 90.961 us; speedup vs baseline: 1.1645x; 1.1645x over previous
//
#include <hip/hip_runtime.h>
#include <cstddef>

namespace {
constexpr int cB = 64, cN = 34, cF = 16, cT = 96, cK = 3, cO = 64;
constexpr int LP = 72;    // u16 pitch (144B rows: 16B-aligned frags, 2-way-free banks)
constexpr int BHP = 88;   // kernel-B H pitch (176B rows: 16B-aligned, 2-way-free)
constexpr int T4 = cT / 4;
constexpr float cEPS = 1e-8f;

typedef __attribute__((ext_vector_type(8))) _Float16 f16x8;
typedef __attribute__((ext_vector_type(8))) short   s16x8;
typedef __attribute__((ext_vector_type(4))) float   f32x4;

__device__ inline unsigned short f2h(float v) {
    _Float16 h = (_Float16)v;
    return __builtin_bit_cast(unsigned short, h);
}
__device__ inline float h2f(unsigned short u) {
    return (float)__builtin_bit_cast(_Float16, u);
}

// H staging address inside d_out (dword index). s = tt*40 + c_dw, s < 160.
// Slots for tile (b,t4) live only in out[:, o<40, 4*t4 .. 4*t4+3] -> each proj_k
// block reads exactly the slots its own final stores later overwrite: race-free.
__device__ inline size_t hstage_idx(int b, int t4, int j, int s) {
    return (((size_t)b * cN + j) * cO + (s >> 2)) * cT + 4 * t4 + (s & 3);
}
}

// ---------------- softmax over axis=2 (i) of st_attention (B,K,N,N) ----------------
__global__ __launch_bounds__(256) void att_softmax_k(const float* __restrict__ st,
                                                     float* __restrict__ att) {
    int idx = blockIdx.x * blockDim.x + threadIdx.x;
    if (idx >= cB * cK * cN) return;
    int j = idx % cN;
    int bk = idx / cN;
    const float* base = st + (size_t)bk * cN * cN + j;
    float v[cN];
    float m = -3.402823466e38f;
#pragma unroll
    for (int i = 0; i < cN; ++i) { v[i] = base[(size_t)i * cN]; m = fmaxf(m, v[i]); }
    float s = 0.f;
#pragma unroll
    for (int i = 0; i < cN; ++i) { v[i] = __expf(v[i] - m); s += v[i]; }
    float inv = 1.f / s;
    float* ob = att + (size_t)bk * cN * cN + j;
#pragma unroll
    for (int i = 0; i < cN; ++i) ob[(size_t)i * cN] = v[i] * inv;
}

// ---------------- kernel A: one block per (b,t); H(34x80 fp16) -> staged in out ----------------
__global__ __launch_bounds__(256, 6) void cheb_h_k(
    const float* __restrict__ x,      // (B,N,F,T)
    const float* __restrict__ att,    // (B,K,N,N) softmaxed
    const float* __restrict__ pos,    // (N,2)
    const float* __restrict__ dist,   // (N,N)
    unsigned* __restrict__ Hst)       // = (unsigned*)out, staging slots
{
    // fp16 matrices [34][LP]; cols >=34 zero (k-pad). A-frag row-overrun reads
    // (rows 34..47, up to ~2000B past an array) must land in allocated LDS ->
    // declaration order matters; M3T overruns into s_gsT (2304B) OK.
    __shared__ __align__(16) unsigned short s_L1[cN * LP];   // A fp32 overlay; L1; then M2T
    __shared__ __align__(16) unsigned short s_L2[cN * LP];   // L2; then M4T
    __shared__ __align__(16) unsigned short s_M1T[cN * LP];  // att1 .* L1, transposed
    __shared__ __align__(16) unsigned short s_M3T[cN * LP];  // att1 .* L2, transposed
    __shared__ __align__(16) unsigned short s_gsT[cF * LP];  // gs^T fp16 (single-writer fill)
    __shared__ float s_d0[cN], s_v1[cN], s_v2[cN], s_p1[cN], s_p2[cN], s_di1[cN], s_di2[cN];

    const int tid = threadIdx.x;
    const int lane = tid & 63;
    const int w = tid >> 6;
    const int lr = lane & 15;
    const int lg = lane >> 4;
    const int kb8 = lg * 8;

    // XCD swizzle (grid 6144, %8==0 -> bijective)
    const unsigned g = blockIdx.x;
    const unsigned lin = (g & 7u) * (cB * cT / 8) + (g >> 3);
    const int b = lin / cT, t = lin % cT;
    const int t4 = t >> 2, tt = t & 3;

    // ---- init: zero matrix arrays (f32x4), stage p-hat/d0/v'/gsT ----
    {
        f32x4 z = (f32x4){0.f, 0.f, 0.f, 0.f};
        for (int i2 = tid; i2 < cN * LP / 8; i2 += 256) {
            ((f32x4*)s_L1)[i2] = z; ((f32x4*)s_L2)[i2] = z;
            ((f32x4*)s_M1T)[i2] = z; ((f32x4*)s_M3T)[i2] = z;
        }
    }
    if (tid < cN) {
        float px = pos[2 * tid], py = pos[2 * tid + 1];
        float pn = sqrtf(px * px + py * py);
        float r = 1.f / fmaxf(pn, cEPS);
        s_p1[tid] = px * r; s_p2[tid] = py * r;
        s_d0[tid] = att[((size_t)b * cK) * cN * cN + tid * cN + tid];
    } else if (tid >= 64 && tid < 64 + cN) {
        int n = tid - 64;
        float x1 = x[(((size_t)b * cN + n) * cF + 1) * cT + t];
        float x2 = x[(((size_t)b * cN + n) * cF + 2) * cT + t];
        float vn = sqrtf(x1 * x1 + x2 * x2);
        float s = vn / fmaxf(vn, cEPS);
        s_v1[n] = x1 * s; s_v2[n] = x2 * s;
    }
    // single-writer gsT fill: data for n<34, zero pads for n>=34 (race lesson, r8)
    for (int idx = tid; idx < cF * LP; idx += 256) {
        int f = idx / LP, n = idx - f * LP;
        unsigned short v = 0;
        if (n < cN) v = f2h(x[(((size_t)b * cN + n) * cF + f) * cT + t]);
        s_gsT[idx] = v;
    }
    __syncthreads();  // b1

    // ---- P2: adjacency A fp32 (compact 34x34) over s_L1 bytes ----
    float* Af = (float*)s_L1;
#pragma unroll
    for (int e = 0; e < 5; ++e) {
        int idx = tid + 256 * e;
        if (idx < cN * cN) {
            int i = idx / cN, m = idx - i * cN;
            float dot = s_v1[i] * s_p1[m] + s_v2[i] * s_p2[m];
            Af[idx] = __fdividef(fmaxf(dot, 0.f), dist[idx]);
        }
    }
    __syncthreads();  // b2

    // ---- P2b: degrees + stash A pairs in regs ----
    if (tid < cN) {
        float s = 0.f;
#pragma unroll
        for (int m = 0; m < cN; ++m) s += Af[tid * cN + m];
        s_di1[tid] = (s > 0.f) ? rsqrtf(fmaxf(s, 1e-12f)) : 0.f;
    } else if (tid >= 64 && tid < 64 + cN) {
        int j = tid - 64;
        float s = 0.f;
#pragma unroll
        for (int i = 0; i < cN; ++i) s += Af[i * cN + j];
        s_di2[j] = (s > 0.f) ? rsqrtf(fmaxf(s, 1e-12f)) : 0.f;
    }
    float aij[5], aji[5];
#pragma unroll
    for (int e = 0; e < 5; ++e) {
        int idx = tid + 256 * e;
        if (idx < cN * cN) {
            int i = idx / cN, j = idx - i * cN;
            aij[e] = Af[idx];
            aji[e] = Af[j * cN + i];
        }
    }
    __syncthreads();  // b3

    // ---- P3: L1/L2 fp16 (re-zero pads dirtied by fp32-A), M1T/M3T = att1.*L^T ----
    const float* att1 = att + ((size_t)b * cK + 1) * cN * cN;
    const float* att2 = att + ((size_t)b * cK + 2) * cN * cN;
#pragma unroll
    for (int e = 0; e < 5; ++e) {
        int idx = tid + 256 * e;
        if (idx < cN * cN) {
            int i = idx / cN, j = idx - i * cN;
            float diag = (i == j) ? 1.f : 0.f;
            float l1 = diag - s_di1[i] * aij[e] * s_di1[j];
            float l2 = diag - s_di2[i] * aji[e] * s_di2[j];
            int rm = i * LP + j, tm = j * LP + i;
            s_L1[rm] = f2h(l1);
            s_L1[rm + cN] = 0;                       // pad cols 34..67
            if (j < 4) s_L1[i * LP + 68 + j] = 0;    // pad cols 68..71
            s_L2[rm] = f2h(l2);
            float a1 = att1[idx];
            s_M1T[tm] = f2h(a1 * l1);
            s_M3T[tm] = f2h(a1 * l2);
        }
    }
    __syncthreads();  // b4

    // ---- P4: C = L@L fp16 MFMA (round-8-validated predicated-scalar B build) ----
    const unsigned short* Ah = (w < 2) ? s_L1 : s_L2;
    const int nnt = (w & 1) ? 1 : 2;
    const int ntb0 = (w & 1) ? 32 : 0;
    f32x4 cd0[3], cd1[3];
#pragma unroll
    for (int mt = 0; mt < 3; ++mt) {
        cd0[mt] = (f32x4){0.f, 0.f, 0.f, 0.f};
        cd1[mt] = (f32x4){0.f, 0.f, 0.f, 0.f};
    }
#pragma unroll
    for (int ks = 0; ks < 2; ++ks) {
        f16x8 fah[3];
#pragma unroll
        for (int mt = 0; mt < 3; ++mt)
            fah[mt] = *(const f16x8*)&Ah[(mt * 16 + lr) * LP + 32 * ks + kb8];
#pragma unroll
        for (int un = 0; un < 2; ++un) {
            if (un == 1 && nnt < 2) break;
            int col = ntb0 + un * 16 + lr;
            s16x8 fbb;
#pragma unroll
            for (int e2 = 0; e2 < 8; ++e2) {
                int kk = 32 * ks + kb8 + e2;
                fbb[e2] = (kk < cN) ? (short)Ah[kk * LP + col] : (short)0;
            }
            f16x8 fb = __builtin_bit_cast(f16x8, fbb);
#pragma unroll
            for (int mt = 0; mt < 3; ++mt) {
                f32x4 acc = un ? cd1[mt] : cd0[mt];
                acc = __builtin_amdgcn_mfma_f32_16x16x32_f16(fah[mt], fb, acc, 0, 0, 0);
                if (un) cd1[mt] = acc; else cd0[mt] = acc;
            }
        }
    }
    __syncthreads();  // b5: all L reads done before M2T/M4T overlay writes

    // ---- P5: M2T = att2 .* (2C1 - I) into s_L1; M4T into s_L2 (dword-packed) ----
    {
        unsigned short* Md = (w < 2) ? s_L1 : s_L2;
#pragma unroll
        for (int un = 0; un < 2; ++un) {
            if (un == 1 && nnt < 2) break;
            int jb = ntb0 + un * 16 + lr;
            if (jb < cN) {
#pragma unroll
                for (int mt = 0; mt < 3; ++mt) {
#pragma unroll
                    for (int h = 0; h < 2; ++h) {
                        int ia = mt * 16 + lg * 4 + 2 * h;   // even; ia+1 <= 33 when ia < 34
                        if (ia < cN) {
                            float dva = h ? (un ? cd1[mt][2] : cd0[mt][2])
                                          : (un ? cd1[mt][0] : cd0[mt][0]);
                            float dvb = h ? (un ? cd1[mt][3] : cd0[mt][3])
                                          : (un ? cd1[mt][1] : cd0[mt][1]);
                            float cva = 2.f * dva - ((ia == jb) ? 1.f : 0.f);
                            float cvb = 2.f * dvb - ((ia + 1 == jb) ? 1.f : 0.f);
                            unsigned lo = f2h(att2[ia * cN + jb] * cva);
                            unsigned hi = f2h(att2[(ia + 1) * cN + jb] * cvb);
                            ((unsigned*)Md)[(jb * LP + ia) >> 1] = lo | (hi << 16);
                        }
                    }
                }
            }
        }
    }
    __syncthreads();  // b6

    // ---- P6: H_p = M_p^T @ gs (wave w -> p=w+1); direct global stores ----
    {
        const unsigned short* Ap = (w == 0) ? s_M1T : (w == 1) ? s_L1
                                 : (w == 2) ? s_M3T : s_L2;
        f32x4 hd[3];
#pragma unroll
        for (int mt = 0; mt < 3; ++mt) hd[mt] = (f32x4){0.f, 0.f, 0.f, 0.f};
#pragma unroll
        for (int ks = 0; ks < 2; ++ks) {
            f16x8 fb = *(const f16x8*)&s_gsT[lr * LP + 32 * ks + kb8];
#pragma unroll
            for (int mt = 0; mt < 3; ++mt) {
                f16x8 fa = *(const f16x8*)&Ap[(mt * 16 + lr) * LP + 32 * ks + kb8];
                hd[mt] = __builtin_amdgcn_mfma_f32_16x16x32_f16(fa, fb, hd[mt], 0, 0, 0);
            }
        }
        // p0 diag block (H cols 0..15 = dwords 0..7), all threads
        for (int idx = tid; idx < cN * 8; idx += 256) {
            int j = idx >> 3, c = idx & 7;
            float d = s_d0[j];
            unsigned lo = f2h(d * h2f(s_gsT[(2 * c) * LP + j]));
            unsigned hi = f2h(d * h2f(s_gsT[(2 * c + 1) * LP + j]));
            Hst[hstage_idx(b, t4, j, tt * 40 + c)] = lo | (hi << 16);
        }
        // pack lane pairs (cols pc+lr, pc+lr^1) -> one dword; split stores by r
        const int pc = 16 * (w + 1);
        const int cdw = (pc >> 1) + (lr >> 1);
#pragma unroll
        for (int mt = 0; mt < 3; ++mt) {
#pragma unroll
            for (int r = 0; r < 4; ++r) {
                int j = mt * 16 + lg * 4 + r;
                unsigned mine = (unsigned)f2h(hd[mt][r]);
                unsigned other = __shfl_xor(mine, 1, 64);
                unsigned dword = (lr & 1) ? ((other & 0xffffu) | (mine << 16))
                                          : (mine | (other << 16));
                bool mystore = ((lr & 1) == 0) ? (r < 2) : (r >= 2);
                if (mystore && j < cN)
                    Hst[hstage_idx(b, t4, j, tt * 40 + cdw)] = dword;
            }
        }
    }
}

// ---------------- kernel B: one block per (b,t4); out = relu(H @ Thcat) ----------------
// Reads its own staging slots into LDS (barrier), then overwrites exactly those
// t-columns with final output -> no cross-block hazard by construction.
__global__ __launch_bounds__(256, 4) void proj_k(
    const unsigned* __restrict__ Hst,   // staging view of out
    const float* __restrict__ Th,       // (K,F,O)
    const float* __restrict__ ThL,      // (K,F,O)
    float* __restrict__ out)            // (B,N,O,T)
{
    __shared__ __align__(16) unsigned short s_H[144 * BHP + 16];  // +16: A-frag overrun pad

    const int tid = threadIdx.x;
    const int lane = tid & 63;
    const int w = tid >> 6;
    const int lr = lane & 15;
    const int lg = lane >> 4;
    const int kb8 = lg * 8;
    const int ocol = w * 16 + lr;

    const unsigned g = blockIdx.x;
    const unsigned lin = (g & 7u) * (cB * T4 / 8) + (g >> 3);
    const int b = lin / T4, t4 = lin % T4;
    const int t0 = t4 * 4;

    // ---- Theta B-fragments fp16 (c = p*16+f; p0 = Th0+ThL0 merged) ----
    f16x8 bfr[3];
#pragma unroll
    for (int s = 0; s < 3; ++s) {
#pragma unroll
        for (int j = 0; j < 8; ++j) {
            int cc = 32 * s + kb8 + j;
            float v = 0.f;
            if (cc < 80) {
                int p = cc >> 4, f = cc & 15;
                if (p == 0)      v = Th[f * cO + ocol] + ThL[f * cO + ocol];
                else if (p == 1) v = Th[(cF + f) * cO + ocol];
                else if (p == 2) v = Th[(2 * cF + f) * cO + ocol];
                else if (p == 3) v = ThL[(cF + f) * cO + ocol];
                else             v = ThL[(2 * cF + f) * cO + ocol];
            }
            bfr[s][j] = (_Float16)v;
        }
    }

    // ---- load H tile from staging slots into pitch-BHP LDS; pads zero ----
    {
        unsigned* dst = (unsigned*)s_H;
        for (int i2 = tid; i2 < 144 * (BHP / 2); i2 += 256) {
            int r = i2 / (BHP / 2), c = i2 - r * (BHP / 2);
            unsigned v = 0u;
            if (r < 136 && c < 40) {
                int j = r >> 2, tt = r & 3;
                v = Hst[hstage_idx(b, t4, j, tt * 40 + c)];
            }
            dst[i2] = v;
        }
    }
    __syncthreads();

    // ---- MFMA: 9 m-tiles x 3 k-steps per wave ----
    f32x4 acc[9];
#pragma unroll
    for (int mt = 0; mt < 9; ++mt) acc[mt] = (f32x4){0.f, 0.f, 0.f, 0.f};
#pragma unroll
    for (int s = 0; s < 3; ++s) {
#pragma unroll
        for (int mt = 0; mt < 9; ++mt) {
            f16x8 a = *(const f16x8*)&s_H[(mt * 16 + lr) * BHP + kb8 + 32 * s];
            acc[mt] = __builtin_amdgcn_mfma_f32_16x16x32_f16(a, bfr[s], acc[mt], 0, 0, 0);
        }
    }

    // ---- stores: acc[mt] = out[j=4mt+lg, ocol, t0..t0+3] -> one float4 ----
#pragma unroll
    for (int mt = 0; mt < 9; ++mt) {
        int j = 4 * mt + lg;
        if (j < cN) {
            float4 v;
            v.x = fmaxf(acc[mt][0], 0.f);
            v.y = fmaxf(acc[mt][1], 0.f);
            v.z = fmaxf(acc[mt][2], 0.f);
            v.w = fmaxf(acc[mt][3], 0.f);
            *(float4*)&out[(((size_t)b * cN + j) * cO + ocol) * cT + t0] = v;
        }
    }
}

extern "C" void kernel_launch(void* const* d_in, const int* in_sizes, int n_in,
                              void* d_out, int out_size, void* d_ws, size_t ws_size,
                              hipStream_t stream) {
    const float* x    = (const float*)d_in[0];
    const float* st   = (const float*)d_in[1];
    const float* pos  = (const float*)d_in[2];
    const float* dist = (const float*)d_in[3];
    const float* Th   = (const float*)d_in[4];
    const float* ThL  = (const float*)d_in[5];
    float* out = (float*)d_out;
    float* att = (float*)d_ws;                 // 888 KB fp32 (proven ws usage)
    unsigned* Hst = (unsigned*)d_out;          // H staged inside out, race-free layout

    att_softmax_k<<<(cB * cK * cN + 255) / 256, 256, 0, stream>>>(st, att);
    cheb_h_k<<<cB * cT, 256, 0, stream>>>(x, att, pos, dist, Hst);
    proj_k<<<cB * T4, 256, 0, stream>>>(Hst, Th, ThL, out);
}